// Round 3
// baseline (1958.265 us; speedup 1.0000x reference)
//
#include <hip/hip_runtime.h>

constexpr int UNITS = 10;
constexpr int TIN = 50;
constexpr int TOUT = 3;
constexpr int G4 = 4 * UNITS;   // 40 gate pre-activations
constexpr int BLK = 256;

__device__ __forceinline__ float sigmoidf_(float x) {
    // v_mul+v_exp_f32 + v_add + v_rcp_f32; |err| few ulp, fine vs 6.4e-5 abs threshold
    return __builtin_amdgcn_rcpf(1.0f + __expf(-x));
}

__global__ __launch_bounds__(BLK, 6) void lstm_ae_kernel(
    const float* __restrict__ X,
    const float* __restrict__ W1, const float* __restrict__ R1, const float* __restrict__ b1,
    const float* __restrict__ W2, const float* __restrict__ R2, const float* __restrict__ b2,
    const float* __restrict__ Wd, const float* __restrict__ bd,
    float* __restrict__ out, int B)
{
    const int b = blockIdx.x * BLK + threadIdx.x;
    if (b >= B) return;

    // Direct global reads of x: lane reads its own contiguous 200B row, 4B per
    // step -> 16 steps of reuse per 64B line, absorbed by L1/L2. No LDS at all
    // -> occupancy capped only by VGPRs (85 cap from launch_bounds -> 6 waves/SIMD).
    const float* __restrict__ xrow = X + (size_t)b * TIN;

    // ---------------- LSTM 1: 50 steps, input dim 1 ----------------
    // Weight indices are compile-time uniform -> scalar s_loads from K$,
    // off the VALU/LDS pipes.
    float h[UNITS], c[UNITS];
    #pragma unroll
    for (int u = 0; u < UNITS; ++u) { h[u] = 0.0f; c[u] = 0.0f; }

    #pragma unroll 1   // keep the ~1.5k-instr body inside I-cache
    for (int t = 0; t < TIN; ++t) {
        const float x = xrow[t];
        float z[G4];
        #pragma unroll
        for (int g = 0; g < G4; ++g) z[g] = fmaf(x, W1[g], b1[g]);
        #pragma unroll
        for (int u = 0; u < UNITS; ++u) {
            const float hu = h[u];
            #pragma unroll
            for (int g = 0; g < G4; ++g) z[g] = fmaf(hu, R1[u * G4 + g], z[g]);
        }
        // gate order i, f, c(g), o
        #pragma unroll
        for (int u = 0; u < UNITS; ++u) {
            const float ig = sigmoidf_(z[u]);
            const float fg = sigmoidf_(z[UNITS + u]);
            const float gg = fmaxf(z[2 * UNITS + u], 0.0f);   // candidate act = relu
            const float og = sigmoidf_(z[3 * UNITS + u]);
            const float cn = fmaf(fg, c[u], ig * gg);
            c[u] = cn;
            h[u] = og * fmaxf(cn, 0.0f);                      // output act = relu
        }
    }

    // ---------------- RepeatVector(3) + LSTM 2 (3 steps) ----------------
    // Same input h every step -> precompute xz2 = h @ W2 + b2 once.
    float xz2[G4];
    #pragma unroll
    for (int g = 0; g < G4; ++g) {
        float a = b2[g];
        #pragma unroll
        for (int u = 0; u < UNITS; ++u) a = fmaf(h[u], W2[u * G4 + g], a);
        xz2[g] = a;
    }

    float h2[UNITS], c2[UNITS];
    float o0;

    // t2 = 0: h_prev = c_prev = 0 -> z = xz2, c = i*g
    {
        float acc = bd[0];
        #pragma unroll
        for (int u = 0; u < UNITS; ++u) {
            const float ig = sigmoidf_(xz2[u]);
            const float gg = fmaxf(xz2[2 * UNITS + u], 0.0f);
            const float og = sigmoidf_(xz2[3 * UNITS + u]);
            const float cn = ig * gg;
            c2[u] = cn;
            const float hn = og * fmaxf(cn, 0.0f);
            h2[u] = hn;
            acc = fmaf(hn, Wd[u], acc);        // TimeDistributed Dense(1)
        }
        o0 = acc;
    }

    // t2 = 1, 2 — per-output-unit formulation keeps live-register count low
    float oacc[2];
    #pragma unroll
    for (int t2 = 0; t2 < 2; ++t2) {
        float hold[UNITS];
        #pragma unroll
        for (int u = 0; u < UNITS; ++u) hold[u] = h2[u];
        float acc = bd[0];
        #pragma unroll
        for (int u = 0; u < UNITS; ++u) {
            float zi = xz2[u];
            float zf = xz2[UNITS + u];
            float zg = xz2[2 * UNITS + u];
            float zo = xz2[3 * UNITS + u];
            #pragma unroll
            for (int v = 0; v < UNITS; ++v) {
                const float hv = hold[v];
                zi = fmaf(hv, R2[v * G4 + u], zi);
                zf = fmaf(hv, R2[v * G4 + UNITS + u], zf);
                zg = fmaf(hv, R2[v * G4 + 2 * UNITS + u], zg);
                zo = fmaf(hv, R2[v * G4 + 3 * UNITS + u], zo);
            }
            const float ig = sigmoidf_(zi);
            const float fg = sigmoidf_(zf);
            const float gg = fmaxf(zg, 0.0f);
            const float og = sigmoidf_(zo);
            const float cn = fmaf(fg, c2[u], ig * gg);
            c2[u] = cn;
            const float hn = og * fmaxf(cn, 0.0f);
            h2[u] = hn;
            acc = fmaf(hn, Wd[u], acc);
        }
        oacc[t2] = acc;
    }

    float* __restrict__ o3 = out + (size_t)b * TOUT;
    o3[0] = o0;
    o3[1] = oacc[0];
    o3[2] = oacc[1];
}

extern "C" void kernel_launch(void* const* d_in, const int* in_sizes, int n_in,
                              void* d_out, int out_size, void* d_ws, size_t ws_size,
                              hipStream_t stream) {
    const float* X  = (const float*)d_in[0];
    const float* W1 = (const float*)d_in[1];
    const float* R1 = (const float*)d_in[2];
    const float* b1 = (const float*)d_in[3];
    const float* W2 = (const float*)d_in[4];
    const float* R2 = (const float*)d_in[5];
    const float* b2 = (const float*)d_in[6];
    const float* Wd = (const float*)d_in[7];
    const float* bd = (const float*)d_in[8];
    float* out = (float*)d_out;

    const int B = in_sizes[0] / TIN;   // 524288
    const int grid = (B + BLK - 1) / BLK;
    lstm_ae_kernel<<<grid, BLK, 0, stream>>>(X, W1, R1, b1, W2, R2, b2, Wd, bd, out, B);
}

// Round 4
// 760.959 us; speedup vs baseline: 2.5734x; 2.5734x over previous
//
#include <hip/hip_runtime.h>

constexpr int UNITS = 10;
constexpr int TIN = 50;
constexpr int TOUT = 3;
constexpr int G4 = 4 * UNITS;   // 40 gate pre-activations
constexpr int BLK = 256;

__device__ __forceinline__ float sigmoidf_(float x) {
    // v_mul + v_exp_f32 + v_add + v_rcp_f32; |err| few ulp, fine vs 6.4e-5 abs threshold
    return __builtin_amdgcn_rcpf(1.0f + __expf(-x));
}

// launch_bounds(256, 4): 128-VGPR budget. Deliberately generous — round 3 showed
// that a tight budget (waves=6 -> cap 85) makes the allocator abandon the
// "z[40] fully live" schedule (VGPR 40, 2.2x slower). With slack it emits the
// round-2 68-VGPR schedule; 68 VGPR + 0 LDS -> 7 waves/SIMD occupancy anyway.
__global__ __launch_bounds__(BLK, 4) void lstm_ae_kernel(
    const float* __restrict__ X,
    const float* __restrict__ W1, const float* __restrict__ R1, const float* __restrict__ b1,
    const float* __restrict__ W2, const float* __restrict__ R2, const float* __restrict__ b2,
    const float* __restrict__ Wd, const float* __restrict__ bd,
    float* __restrict__ out, int B)
{
    const int b = blockIdx.x * BLK + threadIdx.x;
    if (b >= B) return;

    // Direct global reads of x: lane reads its own contiguous 200B row, 4B per
    // step -> 16 steps of reuse per 64B line, absorbed by L1/L2. No LDS at all.
    const float* __restrict__ xrow = X + (size_t)b * TIN;

    // ---------------- LSTM 1: 50 steps, input dim 1 ----------------
    // Weight indices are compile-time uniform -> scalar s_loads from K$,
    // off the VALU/LDS pipes; FMAs read the SGPR operand directly.
    float h[UNITS], c[UNITS];
    #pragma unroll
    for (int u = 0; u < UNITS; ++u) { h[u] = 0.0f; c[u] = 0.0f; }

    #pragma unroll 1   // keep the ~1.5k-instr body inside I-cache
    for (int t = 0; t < TIN; ++t) {
        const float x = xrow[t];
        float z[G4];
        #pragma unroll
        for (int g = 0; g < G4; ++g) z[g] = fmaf(x, W1[g], b1[g]);
        #pragma unroll
        for (int u = 0; u < UNITS; ++u) {
            const float hu = h[u];
            #pragma unroll
            for (int g = 0; g < G4; ++g) z[g] = fmaf(hu, R1[u * G4 + g], z[g]);
        }
        // gate order i, f, c(g), o
        #pragma unroll
        for (int u = 0; u < UNITS; ++u) {
            const float ig = sigmoidf_(z[u]);
            const float fg = sigmoidf_(z[UNITS + u]);
            const float gg = fmaxf(z[2 * UNITS + u], 0.0f);   // candidate act = relu
            const float og = sigmoidf_(z[3 * UNITS + u]);
            const float cn = fmaf(fg, c[u], ig * gg);
            c[u] = cn;
            h[u] = og * fmaxf(cn, 0.0f);                      // output act = relu
        }
    }

    // ---------------- RepeatVector(3) + LSTM 2 (3 steps) ----------------
    // Same input h every step -> precompute xz2 = h @ W2 + b2 once.
    float xz2[G4];
    #pragma unroll
    for (int g = 0; g < G4; ++g) {
        float a = b2[g];
        #pragma unroll
        for (int u = 0; u < UNITS; ++u) a = fmaf(h[u], W2[u * G4 + g], a);
        xz2[g] = a;
    }

    float h2[UNITS], c2[UNITS];
    float o0;

    // t2 = 0: h_prev = c_prev = 0 -> z = xz2, c = i*g
    {
        float acc = bd[0];
        #pragma unroll
        for (int u = 0; u < UNITS; ++u) {
            const float ig = sigmoidf_(xz2[u]);
            const float gg = fmaxf(xz2[2 * UNITS + u], 0.0f);
            const float og = sigmoidf_(xz2[3 * UNITS + u]);
            const float cn = ig * gg;
            c2[u] = cn;
            const float hn = og * fmaxf(cn, 0.0f);
            h2[u] = hn;
            acc = fmaf(hn, Wd[u], acc);        // TimeDistributed Dense(1)
        }
        o0 = acc;
    }

    // t2 = 1, 2 — per-output-unit formulation keeps live-register count low
    float oacc[2];
    #pragma unroll
    for (int t2 = 0; t2 < 2; ++t2) {
        float hold[UNITS];
        #pragma unroll
        for (int u = 0; u < UNITS; ++u) hold[u] = h2[u];
        float acc = bd[0];
        #pragma unroll
        for (int u = 0; u < UNITS; ++u) {
            float zi = xz2[u];
            float zf = xz2[UNITS + u];
            float zg = xz2[2 * UNITS + u];
            float zo = xz2[3 * UNITS + u];
            #pragma unroll
            for (int v = 0; v < UNITS; ++v) {
                const float hv = hold[v];
                zi = fmaf(hv, R2[v * G4 + u], zi);
                zf = fmaf(hv, R2[v * G4 + UNITS + u], zf);
                zg = fmaf(hv, R2[v * G4 + 2 * UNITS + u], zg);
                zo = fmaf(hv, R2[v * G4 + 3 * UNITS + u], zo);
            }
            const float ig = sigmoidf_(zi);
            const float fg = sigmoidf_(zf);
            const float gg = fmaxf(zg, 0.0f);
            const float og = sigmoidf_(zo);
            const float cn = fmaf(fg, c2[u], ig * gg);
            c2[u] = cn;
            const float hn = og * fmaxf(cn, 0.0f);
            h2[u] = hn;
            acc = fmaf(hn, Wd[u], acc);
        }
        oacc[t2] = acc;
    }

    float* __restrict__ o3 = out + (size_t)b * TOUT;
    o3[0] = o0;
    o3[1] = oacc[0];
    o3[2] = oacc[1];
}

extern "C" void kernel_launch(void* const* d_in, const int* in_sizes, int n_in,
                              void* d_out, int out_size, void* d_ws, size_t ws_size,
                              hipStream_t stream) {
    const float* X  = (const float*)d_in[0];
    const float* W1 = (const float*)d_in[1];
    const float* R1 = (const float*)d_in[2];
    const float* b1 = (const float*)d_in[3];
    const float* W2 = (const float*)d_in[4];
    const float* R2 = (const float*)d_in[5];
    const float* b2 = (const float*)d_in[6];
    const float* Wd = (const float*)d_in[7];
    const float* bd = (const float*)d_in[8];
    float* out = (float*)d_out;

    const int B = in_sizes[0] / TIN;   // 524288
    const int grid = (B + BLK - 1) / BLK;
    lstm_ae_kernel<<<grid, BLK, 0, stream>>>(X, W1, R1, b1, W2, R2, b2, Wd, bd, out, B);
}